// Round 1
// baseline (432.473 us; speedup 1.0000x reference)
//
#include <hip/hip_runtime.h>

// BlurPool3D: depthwise 3D conv, filt = ([1,2,1]^3)/64, stride 2, zero-pad 1.
// Input  (N=2, C=64, D=64, H=96, W=96) fp32
// Output (N=2, C=64, OD=32, OH=48, OW=48) fp32
//
// Strategy: one thread per output (y,x) column; roll along z keeping the
// 2D-convolved odd plane in a register (each input plane 2D-conv'd once per
// thread). Integer binomial weights (1,2,1), single final * (1/64).

namespace {
constexpr int D = 64, H = 96, W = 96;
constexpr int OD = 32, OH = 48, OW = 48;
constexpr int HW = H * W;           // 9216
constexpr int PLANE_THREADS = OH * OW;  // 2304 = 9 blocks of 256
}

__global__ __launch_bounds__(256) void blurpool3d_kernel(
    const float* __restrict__ in, float* __restrict__ out)
{
    const int p = blockIdx.x * 256 + threadIdx.x;   // 0..2303
    const int x = p % OW;
    const int y = p / OW;
    const long nc = blockIdx.y;                     // 0..127 (N*C)

    const float* __restrict__ inp = in + nc * (long)(D * HW);
    float* __restrict__ outp = out + nc * (long)(OD * OH * OW);

    const int xb = 2 * x - 1;       // leftmost input col (may be -1 -> pad)
    const int yb = 2 * y - 1;       // topmost input row  (may be -1 -> pad)
    const bool has_left = (x > 0);  // xb >= 0

    // Rolling register: 2D-conv of input plane (2z-1); plane -1 is zero pad.
    float a = 0.0f;

    for (int z = 0; z < OD; ++z) {
        const float* p0 = inp + (2 * z) * HW;       // even plane 2z
        const float* p1 = p0 + HW;                  // odd  plane 2z+1 (<=63)
        float b = 0.0f, c = 0.0f;
        #pragma unroll
        for (int dy = 0; dy < 3; ++dy) {
            const int yy = yb + dy;                 // -1 only when y==0,dy==0
            if (yy >= 0) {
                const float wy = (dy == 1) ? 2.0f : 1.0f;
                const float* r0 = p0 + yy * W + xb;
                const float* r1 = p1 + yy * W + xb;
                const float l0 = has_left ? r0[0] : 0.0f;
                const float l1 = has_left ? r1[0] : 0.0f;
                b += wy * (l0 + 2.0f * r0[1] + r0[2]);
                c += wy * (l1 + 2.0f * r1[1] + r1[2]);
            }
        }
        outp[((long)z * OH + y) * OW + x] = (a + 2.0f * b + c) * (1.0f / 64.0f);
        a = c;   // plane 2z+1 becomes plane 2(z+1)-1
    }
}

extern "C" void kernel_launch(void* const* d_in, const int* in_sizes, int n_in,
                              void* d_out, int out_size, void* d_ws, size_t ws_size,
                              hipStream_t stream)
{
    const float* x = (const float*)d_in[0];
    float* out = (float*)d_out;
    // grid.x: 2304 threads per (n,c) output plane-column set -> 9 blocks of 256
    // grid.y: N*C = 128
    dim3 grid(PLANE_THREADS / 256, 128);
    blurpool3d_kernel<<<grid, dim3(256), 0, stream>>>(x, out);
}

// Round 2
// 410.852 us; speedup vs baseline: 1.0526x; 1.0526x over previous
//
#include <hip/hip_runtime.h>

// BlurPool3D: depthwise 3D conv, filt = ([1,2,1]^3)/64, stride 2, zero-pad 1.
// Input  (N=2, C=64, D=64, H=96, W=96) fp32
// Output (N=2, C=64, OD=32, OH=48, OW=48) fp32
//
// R1: 4 x-outputs per thread via two aligned float4 loads (+1 predicated
// scalar for the left halo), rolling-z register over chunks of 8 output z.
// Block (12,16)=192 threads; grid (3 y-chunks, 4 z-chunks, 128 nc).

namespace {
constexpr int D = 64, H = 96, W = 96;
constexpr int OD = 32, OH = 48, OW = 48;
constexpr int HW = H * W;        // 9216
constexpr int YB = 16;           // y rows per block
constexpr int ZCH = 8;           // z outputs per chunk
}

typedef float f4 __attribute__((ext_vector_type(4)));

__global__ __launch_bounds__(192) void blurpool3d_kernel(
    const float* __restrict__ in, float* __restrict__ out)
{
    const int xg = threadIdx.x;              // 0..11  (4 outputs each)
    const int yl = threadIdx.y;              // 0..15
    const int y  = blockIdx.x * YB + yl;     // 0..47
    const int z0 = blockIdx.y * ZCH;         // 0,8,16,24
    const long nc = blockIdx.z;              // 0..127

    const float* __restrict__ inp = in + nc * (long)(D * HW);
    float* __restrict__ outp = out + nc * (long)(OD * OH * OW)
                                   + (long)y * OW + xg * 4;

    const int xb = xg * 8;                   // cols xb..xb+7 -> h[1..8]; h[0]=col xb-1
    const int yb = 2 * y - 1;
    const int r0i = (y > 0) ? yb : 0;        // clamped (weight 0 when y==0)
    const float w0 = (y > 0) ? 1.0f : 0.0f;
    const int r1i = yb + 1, r2i = yb + 2;    // always in [0,95]
    const bool has_left = (xg > 0);

    // b_j = h[2j] + 2*h[2j+1] + h[2j+2], h[k] = plane[row][xb-1+k]
    auto rowconv = [&](const float* plane, int row) -> f4 {
        const float* r = plane + row * W + xb;
        f4 A = *(const f4*)(r);              // cols xb..xb+3   (16B aligned)
        f4 B = *(const f4*)(r + 4);          // cols xb+4..xb+7 (16B aligned)
        float h0 = has_left ? r[-1] : 0.0f;
        f4 b;
        b.x = h0  + 2.0f * A.x + A.y;
        b.y = A.y + 2.0f * A.z + A.w;
        b.z = A.w + 2.0f * B.x + B.y;
        b.w = B.y + 2.0f * B.z + B.w;
        return b;
    };

    auto planeconv = [&](const float* plane) -> f4 {
        f4 ra = rowconv(plane, r0i);
        f4 rb = rowconv(plane, r1i);
        f4 rc = rowconv(plane, r2i);
        return w0 * ra + 2.0f * rb + rc;
    };

    // Rolling register: 2D conv of input plane (2z-1); plane -1 is zero pad.
    f4 a = {0.0f, 0.0f, 0.0f, 0.0f};
    if (z0 != 0) a = planeconv(inp + (2 * z0 - 1) * HW);

    for (int zi = 0; zi < ZCH; ++zi) {
        const int z = z0 + zi;
        f4 b = planeconv(inp + (2 * z) * HW);
        f4 c = planeconv(inp + (2 * z + 1) * HW);
        f4 o = (a + 2.0f * b + c) * 0.015625f;
        *(f4*)(outp + (long)z * (OH * OW)) = o;
        a = c;
    }
}

extern "C" void kernel_launch(void* const* d_in, const int* in_sizes, int n_in,
                              void* d_out, int out_size, void* d_ws, size_t ws_size,
                              hipStream_t stream)
{
    const float* x = (const float*)d_in[0];
    float* out = (float*)d_out;
    dim3 grid(OH / YB, OD / ZCH, 128);       // (3, 4, 128)
    dim3 block(12, YB);                      // 192 threads = 3 waves
    blurpool3d_kernel<<<grid, block, 0, stream>>>(x, out);
}